// Round 6
// baseline (109.455 us; speedup 1.0000x reference)
//
#include <hip/hip_runtime.h>
#include <hip/hip_cooperative_groups.h>
#include <math.h>

namespace cg = cooperative_groups;

#define RES     32
#define GCELLS  (RES * RES * RES)       // 32768
#define NPTS    32768
#define BATCH   64
#define NPLANES 3
#define EPS_PD  1e-6f
#define WREG_F  25.0f

#define NB      256                     // 1 block per CU
#define NT      1024
#define NWAVES  (NT / 64)
#define PACKED_BYTES ((size_t)BATCH * GCELLS * 4)    // 8 MiB u8x4 table

typedef float        f4 __attribute__((ext_vector_type(4)));
typedef unsigned int u32;
typedef u32          u4 __attribute__((ext_vector_type(4)));

// ---------------------------------------------------------------------------
// helpers
// ---------------------------------------------------------------------------
__device__ __forceinline__ u32 quant_cell(float x, float y, float z, float v) {
    // u = round_half_up((c+0.5)*255) for coords; round(v*255) for vox
    const u32 ux = (u32)fmaf(x, 255.0f, 128.0f);
    const u32 uy = (u32)fmaf(y, 255.0f, 128.0f);
    const u32 uz = (u32)fmaf(z, 255.0f, 128.0f);
    const u32 uv = (u32)fmaf(v, 255.0f, 0.5f);
    return ux | (uy << 8) | (uz << 16) | (uv << 24);
}

// gather + accumulate for 8 points (f = 24 floats) x 3 planes, LDS table
__device__ __forceinline__ float gather_acc(
    const float* f, const u32* tab,
    const float* nx, const float* ny, const float* nz,
    const float* dd, const float* sc)
{
    const float SHIFT  = 0.5f + EPS_PD;
    const float IOFF   = -32.0f * EPS_PD;
    const float INV255 = 1.0f / 255.0f;

    float acc = 0.0f;
    #pragma unroll
    for (int p = 0; p < 8; ++p) {
        const float px = f[3*p], py = f[3*p+1], pz = f[3*p+2];
        const float pxs = px + SHIFT, pys = py + SHIFT, pzs = pz + SHIFT;
        #pragma unroll
        for (int pl = 0; pl < NPLANES; ++pl) {
            const float tt  = (px*nx[pl] + py*ny[pl] + pz*nz[pl] + dd[pl]) * sc[pl];
            const float qxs = fmaf(-tt, nx[pl], pxs);
            const float qys = fmaf(-tt, ny[pl], pys);
            const float qzs = fmaf(-tt, nz[pl], pzs);
            int ix = (int)fmaf(qxs, 32.0f, IOFF);
            int iy = (int)fmaf(qys, 32.0f, IOFF);
            int iz = (int)fmaf(qzs, 32.0f, IOFF);
            ix = min(max(ix, 0), RES - 1);
            iy = min(max(iy, 0), RES - 1);
            iz = min(max(iz, 0), RES - 1);
            const u32 gbyte = ((u32)ix << 12) + ((u32)iy << 7) + ((u32)iz << 2);
            const u32 cell  = *(const u32*)((const char*)tab + gbyte);
            const float dx = fmaf((float)(cell & 255u),         -INV255, qxs);
            const float dy = fmaf((float)((cell >> 8) & 255u),  -INV255, qys);
            const float dz = fmaf((float)((cell >> 16) & 255u), -INV255, qzs);
            const float w  = fmaf((float)(cell >> 24),          -INV255, 1.0f);
            acc = fmaf(__builtin_amdgcn_sqrtf(dx*dx + dy*dy + dz*dz), w, acc);
        }
    }
    return acc;
}

__device__ __forceinline__ float reg_term(const float* __restrict__ planes, int b) {
    float nv[3][3];
    #pragma unroll
    for (int p = 0; p < NPLANES; ++p) {
        const float nxv = planes[((p * BATCH + b) << 2) + 0];
        const float nyv = planes[((p * BATCH + b) << 2) + 1];
        const float nzv = planes[((p * BATCH + b) << 2) + 2];
        float nrm = fmaxf(sqrtf(nxv*nxv + nyv*nyv + nzv*nzv), 1e-12f);
        nv[p][0] = nxv / nrm; nv[p][1] = nyv / nrm; nv[p][2] = nzv / nrm;
    }
    float r = 0.0f;
    #pragma unroll
    for (int i = 0; i < 3; ++i)
        #pragma unroll
        for (int j = 0; j < 3; ++j) {
            const float m = nv[i][j] * nv[j][i] - (i == j ? 1.0f : 0.0f);
            r += m * m;
        }
    return r;
}

// ---------------------------------------------------------------------------
// Cooperative fused kernel: pack -> grid.sync -> stage+gather -> grid.sync
// -> block-0 finalize. 256 blocks x 1024 threads, 1 block/CU.
// ---------------------------------------------------------------------------
__global__ __launch_bounds__(NT, 4) void fused_all_kernel(
    const float* __restrict__ pc,      // (B, N, 3)
    const float* __restrict__ aux,     // (B*G, 3)
    const float* __restrict__ vox,     // (B*G)
    const float* __restrict__ planes,  // (3, B, 4)
    u32* __restrict__ packed,          // (B*G) u8x4 in d_ws
    float* __restrict__ part,          // (NB) in d_ws
    float* __restrict__ out)
{
    __shared__ u32   tab[GCELLS];      // 128 KiB
    __shared__ float wsum[NWAVES];

    const int t    = threadIdx.x;
    const int blk  = blockIdx.x;
    const int xcd  = blk & 7;
    const int slot = blk >> 3;
    const int b    = xcd * 8 + (slot >> 2);    // batch; 4 blocks/batch, same XCD
    const int c    = slot & 3;                 // quarter

    // ---- issue point loads first: HBM latency hides under the pack phase ----
    const f4* pc4 = (const f4*)pc
                  + (((size_t)(b * NPTS + c * 8192) * 3) >> 2)
                  + (size_t)t * 6;
    f4 A[6];
    #pragma unroll
    for (int i = 0; i < 6; ++i) A[i] = __builtin_nontemporal_load(pc4 + i);

    // ---- phase 1: pack quarter c of batch b's table (2 cell-groups/thread) ----
    const size_t gbase = ((size_t)b * GCELLS + (size_t)c * 8192) >> 2;  // group idx
    #pragma unroll
    for (int i = 0; i < 2; ++i) {
        const size_t gk = gbase + (size_t)i * NT + t;
        const f4 a  = __builtin_nontemporal_load((const f4*)aux + 3 * gk + 0);
        const f4 bf = __builtin_nontemporal_load((const f4*)aux + 3 * gk + 1);
        const f4 cf = __builtin_nontemporal_load((const f4*)aux + 3 * gk + 2);
        const f4 v  = __builtin_nontemporal_load((const f4*)vox + gk);
        u4 o;
        o[0] = quant_cell(a.x, a.y, a.z, v.x);
        o[1] = quant_cell(a.w, bf.x, bf.y, v.y);
        o[2] = quant_cell(bf.z, bf.w, cf.x, v.z);
        o[3] = quant_cell(cf.y, cf.z, cf.w, v.w);
        *((u4*)packed + gk) = o;               // normal store: stays in this L2
    }

    cg::this_grid().sync();

    // ---- phase 2: stage full batch table from L2, then gather ----
    const u4* gt = (const u4*)packed + (size_t)b * (GCELLS / 4);
    #pragma unroll
    for (int i = 0; i < 8; ++i) {
        const int k = i * NT + t;
        *(u4*)&tab[k * 4] = gt[k];
    }

    float nx[3], ny[3], nz[3], dd[3], sc[3];
    #pragma unroll
    for (int pl = 0; pl < NPLANES; ++pl) {
        const float* P = planes + ((pl * BATCH + b) << 2);
        nx[pl] = P[0]; ny[pl] = P[1]; nz[pl] = P[2]; dd[pl] = P[3];
        sc[pl] = 2.0f / (nx[pl]*nx[pl] + ny[pl]*ny[pl] + nz[pl]*nz[pl]);
    }

    __syncthreads();

    float acc = gather_acc((const float*)A, tab, nx, ny, nz, dd, sc);

    #pragma unroll
    for (int off = 32; off > 0; off >>= 1)
        acc += __shfl_down(acc, off);
    if ((t & 63) == 0) wsum[t >> 6] = acc;
    __syncthreads();
    if (t == 0) {
        float s = 0.0f;
        #pragma unroll
        for (int w = 0; w < NWAVES; ++w) s += wsum[w];
        part[blk] = s;
    }

    cg::this_grid().sync();

    // ---- phase 3: block 0 reduces partials + reg term -> out[0] ----
    if (blk == 0) {
        float val = (t < NB) ? part[t] * (1.0f / (float)BATCH) : 0.0f;
        if (t < BATCH) val += reg_term(planes, t) * (WREG_F / (float)BATCH);

        #pragma unroll
        for (int off = 32; off > 0; off >>= 1)
            val += __shfl_down(val, off);
        if ((t & 63) == 0) wsum[t >> 6] = val;
        __syncthreads();
        if (t == 0) {
            float s = 0.0f;
            #pragma unroll
            for (int w = 0; w < NWAVES; ++w) s += wsum[w];
            out[0] = s;
        }
    }
}

// ===========================================================================
// Fallback path (non-cooperative): R4's proven 3-kernel pipeline.
// ===========================================================================
#define PACK_BLOCKS 2048

__device__ __forceinline__ int swizzle_chunk(int bid) {
    return (bid & 7) * (PACK_BLOCKS / 8) + (bid >> 3);
}

__global__ __launch_bounds__(256) void pack_u8_kernel(
    const float* __restrict__ aux,
    const float* __restrict__ vox,
    u32* __restrict__ packed)
{
    const int chunk = swizzle_chunk(blockIdx.x);
    const int i = chunk * 256 + threadIdx.x;

    const f4* a4 = (const f4*)aux + (size_t)i * 3;
    const f4 a = __builtin_nontemporal_load(a4 + 0);
    const f4 b = __builtin_nontemporal_load(a4 + 1);
    const f4 c = __builtin_nontemporal_load(a4 + 2);
    const f4 v = __builtin_nontemporal_load((const f4*)vox + i);

    u4 o;
    o[0] = quant_cell(a.x, a.y, a.z, v.x);
    o[1] = quant_cell(a.w, b.x, b.y, v.y);
    o[2] = quant_cell(b.z, b.w, c.x, v.z);
    o[3] = quant_cell(c.y, c.z, c.w, v.w);
    *((u4*)packed + i) = o;
}

__global__ __launch_bounds__(NT, 4) void sym_lds_kernel(
    const float* __restrict__ pc,
    const u32* __restrict__ packed,
    const float* __restrict__ planes,
    float* __restrict__ part)
{
    __shared__ u32   tab[GCELLS];
    __shared__ float wsum[NWAVES];

    const int t    = threadIdx.x;
    const int blk  = blockIdx.x;
    const int xcd  = blk & 7;
    const int slot = blk >> 3;
    const int b    = xcd * 8 + (slot >> 2);
    const int c    = slot & 3;

    const f4* pc4 = (const f4*)pc
                  + (((size_t)(b * NPTS + c * 8192) * 3) >> 2)
                  + (size_t)t * 6;
    f4 A[6];
    #pragma unroll
    for (int i = 0; i < 6; ++i) A[i] = __builtin_nontemporal_load(pc4 + i);

    const u4* gt = (const u4*)packed + (size_t)b * (GCELLS / 4);
    #pragma unroll
    for (int i = 0; i < 8; ++i) {
        const int k = i * NT + t;
        *(u4*)&tab[k * 4] = gt[k];
    }

    float nx[3], ny[3], nz[3], dd[3], sc[3];
    #pragma unroll
    for (int pl = 0; pl < NPLANES; ++pl) {
        const float* P = planes + ((pl * BATCH + b) << 2);
        nx[pl] = P[0]; ny[pl] = P[1]; nz[pl] = P[2]; dd[pl] = P[3];
        sc[pl] = 2.0f / (nx[pl]*nx[pl] + ny[pl]*ny[pl] + nz[pl]*nz[pl]);
    }

    __syncthreads();

    float acc = gather_acc((const float*)A, tab, nx, ny, nz, dd, sc);

    #pragma unroll
    for (int off = 32; off > 0; off >>= 1)
        acc += __shfl_down(acc, off);
    if ((t & 63) == 0) wsum[t >> 6] = acc;
    __syncthreads();
    if (t == 0) {
        float s = 0.0f;
        #pragma unroll
        for (int w = 0; w < NWAVES; ++w) s += wsum[w];
        part[blk] = s;
    }
}

__global__ __launch_bounds__(256) void finalize_kernel(
    const float* __restrict__ part, int n_part,
    const float* __restrict__ planes,
    float* __restrict__ out)
{
    __shared__ float sdata[256];

    float s = 0.0f;
    for (int i = threadIdx.x; i < n_part; i += 256)
        s += part[i];

    float r = 0.0f;
    if (threadIdx.x < BATCH)
        r = reg_term(planes, threadIdx.x);

    float val = s * (1.0f / (float)BATCH) + r * (WREG_F / (float)BATCH);

    sdata[threadIdx.x] = val;
    __syncthreads();
    #pragma unroll
    for (int off = 128; off > 0; off >>= 1) {
        if (threadIdx.x < off) sdata[threadIdx.x] += sdata[threadIdx.x + off];
        __syncthreads();
    }
    if (threadIdx.x == 0) out[0] = sdata[0];
}

// ---------------------------------------------------------------------------
extern "C" void kernel_launch(void* const* d_in, const int* in_sizes, int n_in,
                              void* d_out, int out_size, void* d_ws, size_t ws_size,
                              hipStream_t stream)
{
    const float* pc     = (const float*)d_in[0];
    const float* aux    = (const float*)d_in[1];
    const float* vox    = (const float*)d_in[2];
    const float* planes = (const float*)d_in[3];
    float* out = (float*)d_out;

    u32*   packed = (u32*)d_ws;
    float* part   = (float*)((char*)d_ws + PACKED_BYTES);

    bool coop_ok = false;
    if (ws_size >= PACKED_BYTES + NB * sizeof(float)) {
        void* args[] = {(void*)&pc, (void*)&aux, (void*)&vox, (void*)&planes,
                        (void*)&packed, (void*)&part, (void*)&out};
        hipError_t err = hipLaunchCooperativeKernel(
            (const void*)fused_all_kernel, dim3(NB), dim3(NT), args, 0, stream);
        coop_ok = (err == hipSuccess);
    }

    if (!coop_ok && ws_size >= PACKED_BYTES + NB * sizeof(float)) {
        // proven 3-kernel path
        pack_u8_kernel<<<PACK_BLOCKS, 256, 0, stream>>>(aux, vox, packed);
        sym_lds_kernel<<<NB, NT, 0, stream>>>(pc, packed, planes, part);
        finalize_kernel<<<1, 256, 0, stream>>>(part, NB, planes, out);
    }
}